// Round 4
// baseline (63.386 us; speedup 1.0000x reference)
//
#include <hip/hip_runtime.h>

// ---------------- problem constants ----------------
#define NB    16
#define NCO   16
#define NCI   8
#define DIM   64
#define PDIM  31            // pooled spatial
#define NPOOL 29791.0f      // 31^3
#define NOFF  28            // 27 taps + 1 zero pad
#define KGRP  7             // 28/4 k-groups of K=32 (4 taps x 8 ci)
#define WSCALE 16.0f        // weight pre-scale (power of 2, undone in finalize)

// fast path geometry
#define PHG_N   8                  // pooled-ph groups (4 ph each)
#define PDC_N   8                  // pooled-pd chunks (4 pd each)
#define PARTS_PER_B (PHG_N * PDC_N)   // 64 partials per batch
// LDS tile: 10 d-planes x 10 h-rows x 64 w, chunks of 8 fp8 (8B = 8 ci)
#define TILE_CHUNKS (10*10*64)     // 6400
#define LDS_CHUNKS  6408           // + halo-overrun pad (max read chunk 6401)

typedef __attribute__((ext_vector_type(4))) float f32x4;

__device__ __forceinline__ float wave_reduce_sum(float v) {
#pragma unroll
    for (int off = 32; off > 0; off >>= 1)
        v += __shfl_down(v, off, 64);
    return v;
}

__device__ __forceinline__ unsigned int pack4_fp8(float a, float b, float c, float d) {
    int v = __builtin_amdgcn_cvt_pk_fp8_f32(a, b, 0, false);   // bytes 0,1
    v = __builtin_amdgcn_cvt_pk_fp8_f32(c, d, v, true);        // bytes 2,3
    return (unsigned int)v;
}

// ---------------- fused: wpack + stage(fp32->fp8 LDS) + MFMA conv + pool + partial ----------------
// block = (phg, pdc, b): pd in [4*pdc, 4*pdc+4), oh in [8*phg, 8*phg+8), all ow.
__global__ __launch_bounds__(256, 3)
void conv_fused_kernel(const float* __restrict__ x,
                       const float* __restrict__ w,
                       float* __restrict__ part)
{
    __shared__ __align__(16) unsigned long long lds8[LDS_CHUNKS];
    __shared__ float red[4];

    const int tid   = threadIdx.x;
    const int wave  = tid >> 6;
    const int lane  = tid & 63;
    const int nlane = lane & 15;   // spatial col / co row within tile
    const int o     = lane >> 4;   // tap-sub index within k-group

    const int phg = blockIdx.x;    // 0..7
    const int pdc = blockIdx.y;    // 0..7
    const int b   = blockIdx.z;    // 0..15
    const int oh0 = phg * 8;
    const int d0  = pdc * 8;

    // --- stage raw weights into LDS (alias with x tile), pack per-lane A fragments
    {
        float* wl = reinterpret_cast<float*>(lds8);
#pragma unroll 1
        for (int i = tid; i < NCO * NCI * 27; i += 256) wl[i] = w[i];
    }
    __syncthreads();
    long wfrag[KGRP];
    {
        const float* wl = reinterpret_cast<const float*>(lds8);
#pragma unroll
        for (int g = 0; g < KGRP; ++g) {
            const int off = g * 4 + o;
            float v[8];
#pragma unroll
            for (int ci = 0; ci < NCI; ++ci)
                v[ci] = (off < 27) ? wl[(nlane * NCI + ci) * 27 + off] * (0.5f * WSCALE) : 0.0f;
            const unsigned int lo = pack4_fp8(v[0], v[1], v[2], v[3]);
            const unsigned int hi = pack4_fp8(v[4], v[5], v[6], v[7]);
            wfrag[g] = (long)(((unsigned long long)hi << 32) | lo);
        }
    }
    __syncthreads();

    // --- per-lane LDS byte deltas for this lane's tap in each k-group
    int delta[KGRP];
#pragma unroll
    for (int g = 0; g < KGRP; ++g) {
        int off = g * 4 + o;
        if (off >= 27) off = 0;     // dummy tap (zero weights)
        const int kd = off / 9;
        const int r2 = off % 9;
        const int kh = r2 / 3;
        const int kw = r2 % 3;
        delta[g] = ((kd * 10 + kh) * 64 + kw) * 8;
    }

    // --- stage tile: d in [d0,d0+10) clamped, h in [oh0,oh0+10) clamped, all 64 w, 8 ci -> fp8
    // unit = (row r = dl*10+hl, w-quad q): 8x float4 loads, pack, 2x ds_write_b128
#pragma unroll 1
    for (int u = tid; u < 1600; u += 256) {
        const int r  = u >> 4;          // 0..99
        const int q  = u & 15;
        const int dl = r / 10;
        const int hl = r - dl * 10;
        int d = d0 + dl;  d = (d > 63) ? 63 : d;   // clamp; feeds only masked outputs
        int h = oh0 + hl; h = (h > 63) ? 63 : h;
        const float* src = x + ((((size_t)b * NCI) * DIM + d) * DIM + h) * DIM + q * 4;
        f32x4 v[8];
#pragma unroll
        for (int ci = 0; ci < NCI; ++ci)
            v[ci] = *reinterpret_cast<const f32x4*>(src + (size_t)ci * DIM * DIM * DIM);
        unsigned int ow[8];
#pragma unroll
        for (int j = 0; j < 4; ++j) {
            ow[2 * j]     = pack4_fp8(v[0][j], v[1][j], v[2][j], v[3][j]);
            ow[2 * j + 1] = pack4_fp8(v[4][j], v[5][j], v[6][j], v[7][j]);
        }
        uint4* dst = reinterpret_cast<uint4*>(&lds8[(size_t)r * 64 + q * 4]);
        dst[0] = make_uint4(ow[0], ow[1], ow[2], ow[3]);
        dst[1] = make_uint4(ow[4], ow[5], ow[6], ow[7]);
    }
    __syncthreads();

    // --- compute: wave = pooled-ph sub-index; loop 4 pd values
    float lsum = 0.0f;
    const int ph_global = phg * 4 + wave;
    if (ph_global < PDIM) {
        const char* ldsb = reinterpret_cast<const char*>(lds8);
#pragma unroll 1
        for (int pdl = 0; pdl < 4; ++pdl) {
            const int pd = pdc * 4 + pdl;
            if (pd >= PDIM) break;    // uniform across block (only pdc==7,pdl==3)
#pragma unroll 1
            for (int owt = 0; owt < 4; ++owt) {
                int base_mt[4];
#pragma unroll
                for (int mt = 0; mt < 4; ++mt) {
                    const int od_l = mt >> 1;
                    const int oh_l = 2 * wave + (mt & 1);
                    base_mt[mt] = (((2 * pdl + od_l) * 10 + oh_l) * 64 + owt * 16 + nlane) * 8;
                }
                f32x4 acc[4];
#pragma unroll
                for (int mt = 0; mt < 4; ++mt) acc[mt] = (f32x4){0.f, 0.f, 0.f, 0.f};

#pragma unroll
                for (int g = 0; g < KGRP; ++g) {
#pragma unroll
                    for (int mt = 0; mt < 4; ++mt) {
                        const long bfrag = *reinterpret_cast<const long*>(
                            ldsb + base_mt[mt] + delta[g]);
                        acc[mt] = __builtin_amdgcn_mfma_f32_16x16x32_fp8_fp8(
                            wfrag[g], bfrag, acc[mt], 0, 0, 0);
                    }
                }
                // pool: max over (od pair, oh pair) = the 4 m-tiles, elementwise
                f32x4 mx;
#pragma unroll
                for (int r = 0; r < 4; ++r)
                    mx[r] = fmaxf(fmaxf(acc[0][r], acc[1][r]), fmaxf(acc[2][r], acc[3][r]));
                // max over ow pair: neighbor lane
                float4 pooled;
                pooled.x = fmaxf(mx[0], __shfl_xor(mx[0], 1, 64));
                pooled.y = fmaxf(mx[1], __shfl_xor(mx[1], 1, 64));
                pooled.z = fmaxf(mx[2], __shfl_xor(mx[2], 1, 64));
                pooled.w = fmaxf(mx[3], __shfl_xor(mx[3], 1, 64));
                const int pw = owt * 8 + (nlane >> 1);
                if (((lane & 1) == 0) && (pw < PDIM))
                    lsum += (pooled.x + pooled.y) + (pooled.z + pooled.w);  // 4 co values
            }
        }
    }

    // --- block reduce -> one partial
    const float v = wave_reduce_sum(lsum);
    if (lane == 0) red[wave] = v;
    __syncthreads();
    if (tid == 0)
        part[((size_t)b * PHG_N + phg) * PDC_N + pdc] = (red[0] + red[1]) + (red[2] + red[3]);
}

// ---------------- finalize: 64 partials per batch -> out[b] ----------------
__global__ __launch_bounds__(64)
void finalize3_kernel(const float* __restrict__ part,
                      const float* __restrict__ cb,
                      const float* __restrict__ bias,
                      float* __restrict__ out)
{
    const int b    = blockIdx.x;
    const int lane = threadIdx.x;
    float s = part[(size_t)b * PARTS_PER_B + lane];
    s = wave_reduce_sum(s);
    if (lane == 0) {
        float bc = 0.0f;
#pragma unroll
        for (int c = 0; c < NCO; ++c) bc += 0.5f * cb[c] + bias[c];
        out[b] = s * (1.0f / (WSCALE * NPOOL)) + bc;
    }
}

// ================= fallback fp32 path (implausibly small ws) =================
#define SPATIAL (PDIM*PDIM)
#define NTILE 4

__global__ __launch_bounds__(256)
void conv_pool_fb_kernel(const float* __restrict__ x,
                         const float* __restrict__ w,
                         const float* __restrict__ cb,
                         float* __restrict__ part)
{
    __shared__ float w_s[NCI * 27];
    __shared__ float red[4];
    const int tid  = threadIdx.x;
    const int pd   = blockIdx.x >> 2;
    const int tile = blockIdx.x & 3;
    const int co   = blockIdx.y;
    const int b    = blockIdx.z;
    if (tid < NCI * 27) w_s[tid] = w[co * (NCI * 27) + tid];
    __syncthreads();
    const int s = tile * 256 + tid;
    const bool valid = (s < SPATIAL);
    const int ss = valid ? s : 0;
    const int ph = ss / PDIM;
    const int pw = ss - ph * PDIM;
    const int d0 = pd * 2, h0 = ph * 2, w0 = pw * 2;
    float acc[8];
#pragma unroll
    for (int i = 0; i < 8; ++i) acc[i] = 0.f;
    const float* xb = x + (size_t)b * NCI * DIM * DIM * DIM;
#pragma unroll 1
    for (int ci = 0; ci < NCI; ++ci) {
        float xin[4][4][4];
        const float* xc = xb + (size_t)ci * DIM * DIM * DIM;
#pragma unroll
        for (int dd = 0; dd < 4; ++dd)
#pragma unroll
            for (int hh = 0; hh < 4; ++hh) {
                const float* row = xc + ((d0 + dd) * DIM + (h0 + hh)) * DIM + w0;
                float2 a = *reinterpret_cast<const float2*>(row);
                float2 c = *reinterpret_cast<const float2*>(row + 2);
                xin[dd][hh][0] = a.x; xin[dd][hh][1] = a.y;
                xin[dd][hh][2] = c.x; xin[dd][hh][3] = c.y;
            }
        const float* wc = &w_s[ci * 27];
#pragma unroll
        for (int kd = 0; kd < 3; ++kd)
#pragma unroll
        for (int kh = 0; kh < 3; ++kh)
#pragma unroll
        for (int kw = 0; kw < 3; ++kw) {
            const float wt = wc[(kd * 3 + kh) * 3 + kw];
#pragma unroll
            for (int od = 0; od < 2; ++od)
#pragma unroll
            for (int oh = 0; oh < 2; ++oh)
#pragma unroll
            for (int ow2 = 0; ow2 < 2; ++ow2)
                acc[(od * 2 + oh) * 2 + ow2] += wt * xin[od + kd][oh + kh][ow2 + kw];
        }
    }
    float m = acc[0];
#pragma unroll
    for (int i = 1; i < 8; ++i) m = fmaxf(m, acc[i]);
    m = (m + cb[co]) * 0.5f;
    float contrib = valid ? m : 0.f;
    float v = wave_reduce_sum(contrib);
    if ((tid & 63) == 0) red[tid >> 6] = v;
    __syncthreads();
    if (tid == 0) atomicAdd(&part[b], red[0] + red[1] + red[2] + red[3]);
}

__global__ void zero_acc_kernel(float* __restrict__ part)
{
    if (threadIdx.x < NB) part[threadIdx.x] = 0.f;
}

__global__ void finalize_atomic_kernel(const float* __restrict__ part,
                                       const float* __restrict__ bias,
                                       float* __restrict__ out)
{
    const int t = threadIdx.x;
    if (t < NB) {
        float bs = 0.f;
#pragma unroll
        for (int c = 0; c < NCO; ++c) bs += bias[c];
        out[t] = part[t] * (1.0f / NPOOL) + bs;
    }
}

// ================= launcher =================
extern "C" void kernel_launch(void* const* d_in, const int* in_sizes, int n_in,
                              void* d_out, int out_size, void* d_ws, size_t ws_size,
                              hipStream_t stream) {
    const float* x    = (const float*)d_in[0];
    const float* w    = (const float*)d_in[1];
    const float* cb   = (const float*)d_in[2];
    const float* bias = (const float*)d_in[3];
    float* out = (float*)d_out;

    const size_t needed = (size_t)NB * PARTS_PER_B * sizeof(float);   // 4 KB

    if (ws_size >= needed) {
        float* prt = (float*)d_ws;
        conv_fused_kernel<<<dim3(PHG_N, PDC_N, NB), 256, 0, stream>>>(x, w, prt);
        finalize3_kernel<<<NB, 64, 0, stream>>>(prt, cb, bias, out);
    } else {
        float* prt = (float*)d_ws;
        zero_acc_kernel<<<1, 64, 0, stream>>>(prt);
        dim3 grid(PDIM * NTILE, NCO, NB);
        conv_pool_fb_kernel<<<grid, 256, 0, stream>>>(x, w, cb, prt);
        finalize_atomic_kernel<<<1, 64, 0, stream>>>(prt, bias, out);
    }
}